// Round 1
// baseline (703.974 us; speedup 1.0000x reference)
//
#include <hip/hip_runtime.h>
#include <hip/hip_bf16.h>

#define B_   2
#define T_   2048
#define D_   2048
#define NH_  16
#define NKV_ 4
#define HD_  128
#define KD_  512   // NKV*HD
#define BT_  4096  // B_*T_

typedef __bf16 bf16x8 __attribute__((ext_vector_type(8)));
typedef float  f32x4  __attribute__((ext_vector_type(4)));

__device__ __forceinline__ void gload_lds16(const __hip_bfloat16* g, __hip_bfloat16* l) {
    __builtin_amdgcn_global_load_lds(
        (__attribute__((address_space(1))) void*)(g),
        (__attribute__((address_space(3))) void*)(l),
        16, 0, 0);
}

// ---------------- fp32 -> bf16 convert ----------------
__global__ void f2b_kernel(const float4* __restrict__ in, ushort4* __restrict__ out, int n4) {
    int idx = blockIdx.x * blockDim.x + threadIdx.x;
    int stride = gridDim.x * blockDim.x;
    for (int j = idx; j < n4; j += stride) {
        float4 v = in[j];
        __hip_bfloat16 a = __float2bfloat16(v.x), b = __float2bfloat16(v.y),
                       c = __float2bfloat16(v.z), d = __float2bfloat16(v.w);
        ushort4 o;
        o.x = *(const unsigned short*)&a; o.y = *(const unsigned short*)&b;
        o.z = *(const unsigned short*)&c; o.w = *(const unsigned short*)&d;
        out[j] = o;
    }
}

// ---------------- GEMM: C(MxN) = A(MxK) * B(NxK)^T, bf16 in, f32 out ----------------
// 128x128 tile, BK=32, 256 threads (4 waves, each 64x64 quadrant)
__global__ __launch_bounds__(256)
void gemm_bt(const __hip_bfloat16* __restrict__ A, const __hip_bfloat16* __restrict__ B,
             float* __restrict__ C, int M, int N, int K) {
    __shared__ __attribute__((aligned(16))) __hip_bfloat16 As[128 * 32];
    __shared__ __attribute__((aligned(16))) __hip_bfloat16 Bs[128 * 32];
    const int tid  = threadIdx.x;
    const int w    = tid >> 6;
    const int lane = tid & 63;
    const int lr   = lane & 15;
    const int lk   = lane >> 4;
    const int wr   = w >> 1, wc = w & 1;
    const size_t row0 = (size_t)blockIdx.x * 128;
    const size_t col0 = (size_t)blockIdx.y * 128;

    const __hip_bfloat16* ga = A + (row0 + tid / 4) * K + (tid % 4) * 8;
    const __hip_bfloat16* gb = B + (col0 + tid / 4) * K + (tid % 4) * 8;
    __hip_bfloat16* lA0 = &As[w * 512];
    __hip_bfloat16* lA1 = &As[2048 + w * 512];
    __hip_bfloat16* lB0 = &Bs[w * 512];
    __hip_bfloat16* lB1 = &Bs[2048 + w * 512];

    f32x4 acc[4][4] = {};
    for (int k0 = 0; k0 < K; k0 += 32) {
        gload_lds16(ga + k0,                 lA0);
        gload_lds16(ga + k0 + (size_t)64*K,  lA1);
        gload_lds16(gb + k0,                 lB0);
        gload_lds16(gb + k0 + (size_t)64*K,  lB1);
        __syncthreads();
        bf16x8 af[4], bfr[4];
        #pragma unroll
        for (int m = 0; m < 4; m++)
            af[m] = *(const bf16x8*)&As[(wr * 64 + m * 16 + lr) * 32 + lk * 8];
        #pragma unroll
        for (int n = 0; n < 4; n++)
            bfr[n] = *(const bf16x8*)&Bs[(wc * 64 + n * 16 + lr) * 32 + lk * 8];
        #pragma unroll
        for (int m = 0; m < 4; m++)
            #pragma unroll
            for (int n = 0; n < 4; n++)
                acc[m][n] = __builtin_amdgcn_mfma_f32_16x16x32_bf16(af[m], bfr[n], acc[m][n], 0, 0, 0);
        __syncthreads();
    }
    #pragma unroll
    for (int m = 0; m < 4; m++)
        #pragma unroll
        for (int n = 0; n < 4; n++)
            #pragma unroll
            for (int r = 0; r < 4; r++)
                C[(row0 + wr * 64 + m * 16 + lk * 4 + r) * N + col0 + wc * 64 + n * 16 + lr] = acc[m][n][r];
}

// ---------------- RMSNorm + partial RoPE + gain; v passthrough to bf16 ----------------
// one wave per (b,t,head-slot); slots: 0..15 q, 16..19 k, 20..23 v
__global__ __launch_bounds__(256)
void norm_rope(const float* __restrict__ qf, const float* __restrict__ kf, const float* __restrict__ vf,
               const float* __restrict__ qg,
               __hip_bfloat16* __restrict__ qb, __hip_bfloat16* __restrict__ kb, __hip_bfloat16* __restrict__ vb) {
    int wid  = (blockIdx.x * 256 + threadIdx.x) >> 6;
    int lane = threadIdx.x & 63;
    int bt = wid / 24, hh = wid % 24;
    int b = bt >> 11, t = bt & (T_ - 1);

    const float* row;
    if (hh < NH_)            row = qf + (size_t)bt * D_  + hh * HD_;
    else if (hh < NH_+NKV_)  row = kf + (size_t)bt * KD_ + (hh - NH_) * HD_;
    else                     row = vf + (size_t)bt * KD_ + (hh - NH_ - NKV_) * HD_;

    float2 xv = *(const float2*)(row + lane * 2);

    if (hh >= NH_ + NKV_) {  // v: just convert
        int kv = hh - NH_ - NKV_;
        __hip_bfloat16* o = vb + ((size_t)(b * NKV_ + kv) * T_ + t) * HD_ + lane * 2;
        o[0] = __float2bfloat16(xv.x); o[1] = __float2bfloat16(xv.y);
        return;
    }

    float ss = xv.x * xv.x + xv.y * xv.y;
    #pragma unroll
    for (int off = 32; off; off >>= 1) ss += __shfl_xor(ss, off);
    float rn = rsqrtf(ss * (1.0f / HD_) + 1.1920929e-7f);
    float y0 = xv.x * rn, y1 = xv.y * rn;

    // rope on dims 0..15: lane l<4 holds x1 dims {2l,2l+1}, partner x2 at lane l+4
    float py0 = __shfl_xor(y0, 4), py1 = __shfl_xor(y1, 4);
    float o0 = y0, o1 = y1;
    if (lane < 8) {
        int i0 = (2 * lane) & 7;
        // inv[i] = 10000^(-i/8) = exp2(-i * log2(10000)/8)
        float f0 = (float)t * exp2f(-(float)i0       * 1.66096404744368f);
        float f1 = (float)t * exp2f(-(float)(i0 + 1) * 1.66096404744368f);
        float s0, c0, s1, c1;
        sincosf(f0, &s0, &c0);
        sincosf(f1, &s1, &c1);
        if (lane < 4) { o0 =  y0 * c0 + py0 * s0; o1 =  y1 * c1 + py1 * s1; }
        else          { o0 = -y0 * c0 + py0 * s0; o1 = -y1 * c1 + py1 * s1; }
    }

    if (hh < NH_) {
        // fold gain * 1/sqrt(HD) * log2(e) into q
        float g = qg[hh] * 0.1275174305f;
        o0 *= g; o1 *= g;
        __hip_bfloat16* o = qb + ((size_t)(b * NH_ + hh) * T_ + t) * HD_ + lane * 2;
        o[0] = __float2bfloat16(o0); o[1] = __float2bfloat16(o1);
    } else {
        int kv = hh - NH_;
        __hip_bfloat16* o = kb + ((size_t)(b * NKV_ + kv) * T_ + t) * HD_ + lane * 2;
        o[0] = __float2bfloat16(o0); o[1] = __float2bfloat16(o1);
    }
}

// ---------------- V transpose: [bk][T][HD] -> [bk][HD][T] ----------------
__global__ void vtrans(const __hip_bfloat16* __restrict__ vb, __hip_bfloat16* __restrict__ vt) {
    __shared__ __hip_bfloat16 tile[32][33];
    int bk = blockIdx.z;
    int t0 = blockIdx.x * 32, h0 = blockIdx.y * 32;
    int tx = threadIdx.x, ty = threadIdx.y;  // 32 x 8
    const __hip_bfloat16* src = vb + ((size_t)bk * T_ + t0) * HD_ + h0;
    #pragma unroll
    for (int j = 0; j < 4; j++) tile[ty + j * 8][tx] = src[(size_t)(ty + j * 8) * HD_ + tx];
    __syncthreads();
    __hip_bfloat16* dst = vt + ((size_t)bk * HD_ + h0) * T_ + t0;
    #pragma unroll
    for (int j = 0; j < 4; j++) dst[(size_t)(ty + j * 8) * T_ + tx] = tile[tx][ty + j * 8];
}

// ---------------- causal GQA flash attention ----------------
// one wave per 16-row q tile; kv tiles of 32; scores already scaled (gain/sqrt(HD)/log2e folded into q)
__global__ __launch_bounds__(256)
void attn_fwd(const __hip_bfloat16* __restrict__ qb, const __hip_bfloat16* __restrict__ kb,
              const __hip_bfloat16* __restrict__ vt, __hip_bfloat16* __restrict__ yb) {
    __shared__ __attribute__((aligned(16))) __hip_bfloat16 Plds[4][16 * 32];
    const int w = threadIdx.x >> 6, lane = threadIdx.x & 63;
    const int lr = lane & 15, lk = lane >> 4;
    const int widx = blockIdx.x * 4 + w;
    const int nqt = T_ / 16;
    const int qt = widx % nqt;
    const int h  = (widx / nqt) % NH_;
    const int b  = widx / (nqt * NH_);
    const int kv = h >> 2;
    const int q0 = qt * 16;

    const __hip_bfloat16* qp = qb + ((size_t)(b * NH_ + h) * T_ + q0) * HD_;
    const __hip_bfloat16* kp = kb + (size_t)(b * NKV_ + kv) * T_ * HD_;
    const __hip_bfloat16* vp = vt + (size_t)(b * NKV_ + kv) * HD_ * T_;

    bf16x8 qfr[4];
    #pragma unroll
    for (int ks = 0; ks < 4; ks++)
        qfr[ks] = *(const bf16x8*)(qp + lr * HD_ + ks * 32 + lk * 8);

    f32x4 acc[8] = {};
    float mrow[4] = {-1e30f, -1e30f, -1e30f, -1e30f};
    float srow[4] = {0.f, 0.f, 0.f, 0.f};

    const int nt = (q0 + 16 + 31) >> 5;
    for (int kt = 0; kt < nt; ++kt) {
        const int kbase = kt * 32;
        f32x4 s0 = {0.f, 0.f, 0.f, 0.f}, s1 = {0.f, 0.f, 0.f, 0.f};
        const int kr0 = kbase + lr;
        const int kr1 = kbase + 16 + lr;
        const __hip_bfloat16* kpr0 = kp + (size_t)(kr0 < T_ ? kr0 : T_ - 1) * HD_ + lk * 8;
        const __hip_bfloat16* kpr1 = kp + (size_t)(kr1 < T_ ? kr1 : T_ - 1) * HD_ + lk * 8;
        #pragma unroll
        for (int ks = 0; ks < 4; ks++) {
            bf16x8 k0f = *(const bf16x8*)(kpr0 + ks * 32);
            bf16x8 k1f = *(const bf16x8*)(kpr1 + ks * 32);
            s0 = __builtin_amdgcn_mfma_f32_16x16x32_bf16(qfr[ks], k0f, s0, 0, 0, 0);
            s1 = __builtin_amdgcn_mfma_f32_16x16x32_bf16(qfr[ks], k1f, s1, 0, 0, 0);
        }
        float p0[4], p1[4], corr[4];
        #pragma unroll
        for (int r = 0; r < 4; r++) {
            const int qrow = q0 + lk * 4 + r;
            float v0 = (kr0 <= qrow) ? s0[r] : -1e30f;
            float v1 = (kr1 <= qrow) ? s1[r] : -1e30f;
            float mx = fmaxf(v0, v1);
            #pragma unroll
            for (int off = 8; off; off >>= 1) mx = fmaxf(mx, __shfl_xor(mx, off));
            float mn = fmaxf(mrow[r], mx);
            corr[r] = exp2f(mrow[r] - mn);
            mrow[r] = mn;
            p0[r] = exp2f(v0 - mn);
            p1[r] = exp2f(v1 - mn);
            float rs = p0[r] + p1[r];
            #pragma unroll
            for (int off = 8; off; off >>= 1) rs += __shfl_xor(rs, off);
            srow[r] = srow[r] * corr[r] + rs;
        }
        #pragma unroll
        for (int ht = 0; ht < 8; ht++) {
            acc[ht][0] *= corr[0]; acc[ht][1] *= corr[1];
            acc[ht][2] *= corr[2]; acc[ht][3] *= corr[3];
        }
        // P (16q x 32k) -> LDS, bf16
        __hip_bfloat16* pl = &Plds[w][0];
        #pragma unroll
        for (int r = 0; r < 4; r++) {
            pl[(lk * 4 + r) * 32 + lr]      = __float2bfloat16(p0[r]);
            pl[(lk * 4 + r) * 32 + 16 + lr] = __float2bfloat16(p1[r]);
        }
        bf16x8 pa = *(const bf16x8*)(pl + lr * 32 + lk * 8);
        int tcol = kbase + lk * 8; if (tcol > T_ - 8) tcol = T_ - 8;
        #pragma unroll
        for (int ht = 0; ht < 8; ht++) {
            bf16x8 bv = *(const bf16x8*)(vp + (size_t)(ht * 16 + lr) * T_ + tcol);
            acc[ht] = __builtin_amdgcn_mfma_f32_16x16x32_bf16(pa, bv, acc[ht], 0, 0, 0);
        }
    }
    float rinv[4];
    #pragma unroll
    for (int r = 0; r < 4; r++) rinv[r] = 1.0f / srow[r];
    #pragma unroll
    for (int ht = 0; ht < 8; ht++)
        #pragma unroll
        for (int r = 0; r < 4; r++)
            yb[((size_t)b * T_ + q0 + lk * 4 + r) * D_ + h * HD_ + ht * 16 + lr] =
                __float2bfloat16(acc[ht][r] * rinv[r]);
}

extern "C" void kernel_launch(void* const* d_in, const int* in_sizes, int n_in,
                              void* d_out, int out_size, void* d_ws, size_t ws_size,
                              hipStream_t stream) {
    (void)in_sizes; (void)n_in; (void)out_size; (void)ws_size;
    const float* x  = (const float*)d_in[0];
    const float* wq = (const float*)d_in[1];
    const float* wk = (const float*)d_in[2];
    const float* wv = (const float*)d_in[3];
    const float* wp = (const float*)d_in[4];
    const float* qg = (const float*)d_in[5];
    float* out = (float*)d_out;

    char* ws = (char*)d_ws;
    size_t off = 0;
    auto alloc = [&](size_t bytes) { char* p = ws + off; off += (bytes + 255) & ~(size_t)255; return p; };

    __hip_bfloat16* xb  = (__hip_bfloat16*)alloc((size_t)BT_ * D_ * 2);   // 16.8 MB (later: yb alias)
    __hip_bfloat16* wqb = (__hip_bfloat16*)alloc((size_t)D_ * D_ * 2);    //  8.4 MB (later: vb/vt alias)
    __hip_bfloat16* wkb = (__hip_bfloat16*)alloc((size_t)KD_ * D_ * 2);
    __hip_bfloat16* wvb = (__hip_bfloat16*)alloc((size_t)KD_ * D_ * 2);
    __hip_bfloat16* wpb = (__hip_bfloat16*)alloc((size_t)D_ * D_ * 2);
    float* qf = (float*)alloc((size_t)BT_ * D_ * 4);                      // 33.6 MB
    float* kf = (float*)alloc((size_t)BT_ * KD_ * 4);
    float* vf = (float*)alloc((size_t)BT_ * KD_ * 4);
    __hip_bfloat16* qbb = (__hip_bfloat16*)alloc((size_t)BT_ * D_ * 2);
    __hip_bfloat16* kbb = (__hip_bfloat16*)alloc((size_t)BT_ * KD_ * 2);
    // aliases (lifetimes disjoint on the sequential stream):
    __hip_bfloat16* ybb = xb;                   // yb written after xb's last read
    __hip_bfloat16* vbb = wqb;                  // wqb dead after q-projection
    __hip_bfloat16* vtb = wqb + (size_t)B_ * NKV_ * T_ * HD_;

    // fp32 -> bf16 converts
    f2b_kernel<<<2048, 256, 0, stream>>>((const float4*)x,  (ushort4*)xb,  BT_ * D_ / 4);
    f2b_kernel<<<2048, 256, 0, stream>>>((const float4*)wq, (ushort4*)wqb, D_ * D_ / 4);
    f2b_kernel<<<2048, 256, 0, stream>>>((const float4*)wk, (ushort4*)wkb, KD_ * D_ / 4);
    f2b_kernel<<<2048, 256, 0, stream>>>((const float4*)wv, (ushort4*)wvb, KD_ * D_ / 4);
    f2b_kernel<<<2048, 256, 0, stream>>>((const float4*)wp, (ushort4*)wpb, D_ * D_ / 4);

    // projections
    dim3 gq(BT_ / 128, D_ / 128);
    gemm_bt<<<gq, 256, 0, stream>>>(xb, wqb, qf, BT_, D_, D_);
    dim3 gkv(BT_ / 128, KD_ / 128);
    gemm_bt<<<gkv, 256, 0, stream>>>(xb, wkb, kf, BT_, KD_, D_);
    gemm_bt<<<gkv, 256, 0, stream>>>(xb, wvb, vf, BT_, KD_, D_);

    // norm + rope + gain (+ v convert)
    norm_rope<<<(BT_ * 24) / 4, 256, 0, stream>>>(qf, kf, vf, qg, qbb, kbb, vbb);

    // V transpose for PV fragments
    dim3 gt(T_ / 32, HD_ / 32, B_ * NKV_);
    vtrans<<<gt, dim3(32, 8), 0, stream>>>(vbb, vtb);

    // attention
    attn_fwd<<<(B_ * NH_ * (T_ / 16)) / 4, 256, 0, stream>>>(qbb, kbb, vtb, ybb);

    // output projection -> f32 out
    gemm_bt<<<gq, 256, 0, stream>>>(ybb, wpb, out, BT_, D_, D_);
}

// Round 2
// 408.507 us; speedup vs baseline: 1.7233x; 1.7233x over previous
//
#include <hip/hip_runtime.h>
#include <hip/hip_bf16.h>

#define B_   2
#define T_   2048
#define D_   2048
#define NH_  16
#define NKV_ 4
#define HD_  128
#define KD_  512   // NKV*HD
#define BT_  4096  // B_*T_

typedef __bf16 bf16x8 __attribute__((ext_vector_type(8)));
typedef float  f32x4  __attribute__((ext_vector_type(4)));
typedef float  f32x16 __attribute__((ext_vector_type(16)));

__device__ __forceinline__ void gload_lds16(const __hip_bfloat16* g, __hip_bfloat16* l) {
    __builtin_amdgcn_global_load_lds(
        (__attribute__((address_space(1))) void*)(g),
        (__attribute__((address_space(3))) void*)(l),
        16, 0, 0);
}

// ---------------- fp32 -> bf16 convert ----------------
__global__ void f2b_kernel(const float4* __restrict__ in, ushort4* __restrict__ out, int n4) {
    int idx = blockIdx.x * blockDim.x + threadIdx.x;
    int stride = gridDim.x * blockDim.x;
    for (int j = idx; j < n4; j += stride) {
        float4 v = in[j];
        __hip_bfloat16 a = __float2bfloat16(v.x), b = __float2bfloat16(v.y),
                       c = __float2bfloat16(v.z), d = __float2bfloat16(v.w);
        ushort4 o;
        o.x = *(const unsigned short*)&a; o.y = *(const unsigned short*)&b;
        o.z = *(const unsigned short*)&c; o.w = *(const unsigned short*)&d;
        out[j] = o;
    }
}

// ---------------- GEMM: C(MxN) = A(MxK) * B(NxK)^T, bf16 in, f32 out ----------------
__global__ __launch_bounds__(256)
void gemm_bt(const __hip_bfloat16* __restrict__ A, const __hip_bfloat16* __restrict__ B,
             float* __restrict__ C, int M, int N, int K) {
    __shared__ __attribute__((aligned(16))) __hip_bfloat16 As[128 * 32];
    __shared__ __attribute__((aligned(16))) __hip_bfloat16 Bs[128 * 32];
    const int tid  = threadIdx.x;
    const int w    = tid >> 6;
    const int lane = tid & 63;
    const int lr   = lane & 15;
    const int lk   = lane >> 4;
    const int wr   = w >> 1, wc = w & 1;
    const size_t row0 = (size_t)blockIdx.x * 128;
    const size_t col0 = (size_t)blockIdx.y * 128;

    const __hip_bfloat16* ga = A + (row0 + tid / 4) * K + (tid % 4) * 8;
    const __hip_bfloat16* gb = B + (col0 + tid / 4) * K + (tid % 4) * 8;
    __hip_bfloat16* lA0 = &As[w * 512];
    __hip_bfloat16* lA1 = &As[2048 + w * 512];
    __hip_bfloat16* lB0 = &Bs[w * 512];
    __hip_bfloat16* lB1 = &Bs[2048 + w * 512];

    f32x4 acc[4][4] = {};
    for (int k0 = 0; k0 < K; k0 += 32) {
        gload_lds16(ga + k0,                 lA0);
        gload_lds16(ga + k0 + (size_t)64*K,  lA1);
        gload_lds16(gb + k0,                 lB0);
        gload_lds16(gb + k0 + (size_t)64*K,  lB1);
        __syncthreads();
        bf16x8 af[4], bfr[4];
        #pragma unroll
        for (int m = 0; m < 4; m++)
            af[m] = *(const bf16x8*)&As[(wr * 64 + m * 16 + lr) * 32 + lk * 8];
        #pragma unroll
        for (int n = 0; n < 4; n++)
            bfr[n] = *(const bf16x8*)&Bs[(wc * 64 + n * 16 + lr) * 32 + lk * 8];
        #pragma unroll
        for (int m = 0; m < 4; m++)
            #pragma unroll
            for (int n = 0; n < 4; n++)
                acc[m][n] = __builtin_amdgcn_mfma_f32_16x16x32_bf16(af[m], bfr[n], acc[m][n], 0, 0, 0);
        __syncthreads();
    }
    #pragma unroll
    for (int m = 0; m < 4; m++)
        #pragma unroll
        for (int n = 0; n < 4; n++)
            #pragma unroll
            for (int r = 0; r < 4; r++)
                C[(row0 + wr * 64 + m * 16 + lk * 4 + r) * N + col0 + wc * 64 + n * 16 + lr] = acc[m][n][r];
}

// ---------------- RMSNorm + partial RoPE + gain; v passthrough to bf16 ----------------
__global__ __launch_bounds__(256)
void norm_rope(const float* __restrict__ qf, const float* __restrict__ kf, const float* __restrict__ vf,
               const float* __restrict__ qg,
               __hip_bfloat16* __restrict__ qb, __hip_bfloat16* __restrict__ kb, __hip_bfloat16* __restrict__ vb) {
    int wid  = (blockIdx.x * 256 + threadIdx.x) >> 6;
    int lane = threadIdx.x & 63;
    int bt = wid / 24, hh = wid % 24;
    int b = bt >> 11, t = bt & (T_ - 1);

    const float* row;
    if (hh < NH_)            row = qf + (size_t)bt * D_  + hh * HD_;
    else if (hh < NH_+NKV_)  row = kf + (size_t)bt * KD_ + (hh - NH_) * HD_;
    else                     row = vf + (size_t)bt * KD_ + (hh - NH_ - NKV_) * HD_;

    float2 xv = *(const float2*)(row + lane * 2);

    if (hh >= NH_ + NKV_) {  // v: just convert
        int kv = hh - NH_ - NKV_;
        __hip_bfloat16* o = vb + ((size_t)(b * NKV_ + kv) * T_ + t) * HD_ + lane * 2;
        o[0] = __float2bfloat16(xv.x); o[1] = __float2bfloat16(xv.y);
        return;
    }

    float ss = xv.x * xv.x + xv.y * xv.y;
    #pragma unroll
    for (int off = 32; off; off >>= 1) ss += __shfl_xor(ss, off);
    float rn = rsqrtf(ss * (1.0f / HD_) + 1.1920929e-7f);
    float y0 = xv.x * rn, y1 = xv.y * rn;

    float py0 = __shfl_xor(y0, 4), py1 = __shfl_xor(y1, 4);
    float o0 = y0, o1 = y1;
    if (lane < 8) {
        int i0 = (2 * lane) & 7;
        float f0 = (float)t * exp2f(-(float)i0       * 1.66096404744368f);
        float f1 = (float)t * exp2f(-(float)(i0 + 1) * 1.66096404744368f);
        float s0, c0, s1, c1;
        sincosf(f0, &s0, &c0);
        sincosf(f1, &s1, &c1);
        if (lane < 4) { o0 =  y0 * c0 + py0 * s0; o1 =  y1 * c1 + py1 * s1; }
        else          { o0 = -y0 * c0 + py0 * s0; o1 = -y1 * c1 + py1 * s1; }
    }

    if (hh < NH_) {
        // fold gain * 1/sqrt(HD) * log2(e) into q
        float g = qg[hh] * 0.1275174305f;
        o0 *= g; o1 *= g;
        __hip_bfloat16* o = qb + ((size_t)(b * NH_ + hh) * T_ + t) * HD_ + lane * 2;
        o[0] = __float2bfloat16(o0); o[1] = __float2bfloat16(o1);
    } else {
        int kv = hh - NH_;
        __hip_bfloat16* o = kb + ((size_t)(b * NKV_ + kv) * T_ + t) * HD_ + lane * 2;
        o[0] = __float2bfloat16(o0); o[1] = __float2bfloat16(o1);
    }
}

// ---------------- V transpose: [bk][T][HD] -> [bk][HD][T] ----------------
__global__ void vtrans(const __hip_bfloat16* __restrict__ vb, __hip_bfloat16* __restrict__ vt) {
    __shared__ __hip_bfloat16 tile[32][33];
    int bk = blockIdx.z;
    int t0 = blockIdx.x * 32, h0 = blockIdx.y * 32;
    int tx = threadIdx.x, ty = threadIdx.y;  // 32 x 8
    const __hip_bfloat16* src = vb + ((size_t)bk * T_ + t0) * HD_ + h0;
    #pragma unroll
    for (int j = 0; j < 4; j++) tile[ty + j * 8][tx] = src[(size_t)(ty + j * 8) * HD_ + tx];
    __syncthreads();
    __hip_bfloat16* dst = vt + ((size_t)bk * HD_ + h0) * T_ + t0;
    #pragma unroll
    for (int j = 0; j < 4; j++) dst[(size_t)(ty + j * 8) * T_ + tx] = tile[tx][ty + j * 8];
}

// ---------------- causal GQA flash attention (swapped-QK, 32x32 MFMA, no LDS) ----------------
__device__ __forceinline__ unsigned pkbf(float a, float b) {
    __hip_bfloat16 x = __float2bfloat16(a), y = __float2bfloat16(b);
    unsigned short xu = *(const unsigned short*)&x, yu = *(const unsigned short*)&y;
    return (unsigned)xu | ((unsigned)yu << 16);
}

union U8u { unsigned u[4]; bf16x8 v; };

// one wave per 32-row q chunk; kv tiles of 32; scores pre-scaled (gain/sqrt(HD)/log2e in q)
__global__ __launch_bounds__(256, 2)
void attn_fwd(const __hip_bfloat16* __restrict__ qb, const __hip_bfloat16* __restrict__ kb,
              const __hip_bfloat16* __restrict__ vt, __hip_bfloat16* __restrict__ yb) {
    const int w = threadIdx.x >> 6, lane = threadIdx.x & 63;
    const int l31 = lane & 31, hi = lane >> 5;
    const int bid = blockIdx.x;
    // XCD-grouped head mapping: 16 blocks of a head share one XCD (1MB K/V in its L2)
    const int xcd = bid & 7, j = bid >> 3;
    const int head = xcd * 4 + (j & 3);    // 0..31
    const int i = j >> 2;                  // 0..15
    const int b = head >> 4, h = head & 15;
    const int kvh = h >> 2;
    // balanced chunk map: block's 4 waves do {i, 31-i, 32+i, 63-i} -> 130 tiles/block
    const int c = (w == 0) ? i : (w == 1) ? 31 - i : (w == 2) ? 32 + i : 63 - i;
    const int qa = c * 32;

    const __hip_bfloat16* qp = qb + ((size_t)(b * NH_ + h) * T_ + qa) * HD_;
    const __hip_bfloat16* kp = kb + (size_t)(b * NKV_ + kvh) * T_ * HD_;
    const __hip_bfloat16* vp = vt + (size_t)(b * NKV_ + kvh) * HD_ * T_ + (size_t)l31 * T_;

    bf16x8 qfr[8];
    #pragma unroll
    for (int hb = 0; hb < 8; ++hb)
        qfr[hb] = *(const bf16x8*)(qp + (size_t)l31 * HD_ + hb * 16 + hi * 8);

    f32x16 o0 = {}, o1 = {}, o2 = {}, o3 = {};
    float m = -1e30f, s = 0.f;

    for (int kt = 0; kt <= c; ++kt) {
        const int kvb = kt * 32;
        // S^T[kv][q] = sum_hd K[kv][hd] * Q[q][hd]
        f32x16 sa = {};
        const __hip_bfloat16* kpt = kp + (size_t)(kvb + l31) * HD_ + hi * 8;
        #pragma unroll
        for (int hb = 0; hb < 8; ++hb) {
            bf16x8 kf = *(const bf16x8*)(kpt + hb * 16);
            sa = __builtin_amdgcn_mfma_f32_32x32x16_bf16(kf, qfr[hb], sa, 0, 0, 0);
        }
        if (kt == c) {  // diagonal tile: mask kv > q (relative indices)
            #pragma unroll
            for (int r = 0; r < 16; ++r) {
                int kvrel = (r & 3) + 8 * (r >> 2) + 4 * hi;
                if (kvrel > l31) sa[r] = -1e30f;
            }
        }
        float pm = sa[0];
        #pragma unroll
        for (int r = 1; r < 16; ++r) pm = fmaxf(pm, sa[r]);
        pm = fmaxf(pm, __shfl_xor(pm, 32));
        if (!__all(pm <= m + 8.f)) {   // deferred rescale (THR=8 in log2 domain)
            float mn = fmaxf(m, pm);
            float corr = exp2f(m - mn);
            s *= corr;
            #pragma unroll
            for (int r = 0; r < 16; ++r) { o0[r] *= corr; o1[r] *= corr; o2[r] *= corr; o3[r] *= corr; }
            m = mn;
        }
        float p[16]; float rs = 0.f;
        #pragma unroll
        for (int r = 0; r < 16; ++r) { p[r] = exp2f(sa[r] - m); rs += p[r]; }
        rs += __shfl_xor(rs, 32);
        s += rs;
        // pack P -> bf16 PV B-fragments (lane pair l <-> l^32 exchange)
        unsigned pk[8];
        #pragma unroll
        for (int jj = 0; jj < 8; ++jj) pk[jj] = pkbf(p[2 * jj], p[2 * jj + 1]);
        unsigned pks[8];
        #pragma unroll
        for (int jj = 0; jj < 8; ++jj) pks[jj] = (unsigned)__shfl_xor((int)pk[jj], 32);
        U8u pa0, pa1;
        pa0.u[0] = hi ? pks[2] : pk[0];
        pa0.u[1] = hi ? pks[3] : pk[1];
        pa0.u[2] = hi ? pk[2]  : pks[0];
        pa0.u[3] = hi ? pk[3]  : pks[1];
        pa1.u[0] = hi ? pks[6] : pk[4];
        pa1.u[1] = hi ? pks[7] : pk[5];
        pa1.u[2] = hi ? pk[6]  : pks[4];
        pa1.u[3] = hi ? pk[7]  : pks[5];
        // O^T[d][q] += V^T[d][kv] * P[kv][q]
        const __hip_bfloat16* vpt = vp + kvb + hi * 8;
        {
            bf16x8 vf0 = *(const bf16x8*)(vpt);
            bf16x8 vf1 = *(const bf16x8*)(vpt + 16);
            o0 = __builtin_amdgcn_mfma_f32_32x32x16_bf16(vf0, pa0.v, o0, 0, 0, 0);
            o0 = __builtin_amdgcn_mfma_f32_32x32x16_bf16(vf1, pa1.v, o0, 0, 0, 0);
        }
        {
            bf16x8 vf0 = *(const bf16x8*)(vpt + (size_t)32 * T_);
            bf16x8 vf1 = *(const bf16x8*)(vpt + (size_t)32 * T_ + 16);
            o1 = __builtin_amdgcn_mfma_f32_32x32x16_bf16(vf0, pa0.v, o1, 0, 0, 0);
            o1 = __builtin_amdgcn_mfma_f32_32x32x16_bf16(vf1, pa1.v, o1, 0, 0, 0);
        }
        {
            bf16x8 vf0 = *(const bf16x8*)(vpt + (size_t)64 * T_);
            bf16x8 vf1 = *(const bf16x8*)(vpt + (size_t)64 * T_ + 16);
            o2 = __builtin_amdgcn_mfma_f32_32x32x16_bf16(vf0, pa0.v, o2, 0, 0, 0);
            o2 = __builtin_amdgcn_mfma_f32_32x32x16_bf16(vf1, pa1.v, o2, 0, 0, 0);
        }
        {
            bf16x8 vf0 = *(const bf16x8*)(vpt + (size_t)96 * T_);
            bf16x8 vf1 = *(const bf16x8*)(vpt + (size_t)96 * T_ + 16);
            o3 = __builtin_amdgcn_mfma_f32_32x32x16_bf16(vf0, pa0.v, o3, 0, 0, 0);
            o3 = __builtin_amdgcn_mfma_f32_32x32x16_bf16(vf1, pa1.v, o3, 0, 0, 0);
        }
    }

    float inv = 1.0f / s;
    __hip_bfloat16* yrow = yb + ((size_t)b * T_ + qa + l31) * D_ + h * HD_;
    #define WRITE_DB(ON, DB)                                                        \
        _Pragma("unroll")                                                           \
        for (int r4 = 0; r4 < 4; ++r4) {                                            \
            ushort4 u;                                                              \
            __hip_bfloat16 e0 = __float2bfloat16(ON[4*r4+0] * inv);                 \
            __hip_bfloat16 e1 = __float2bfloat16(ON[4*r4+1] * inv);                 \
            __hip_bfloat16 e2 = __float2bfloat16(ON[4*r4+2] * inv);                 \
            __hip_bfloat16 e3 = __float2bfloat16(ON[4*r4+3] * inv);                 \
            u.x = *(const unsigned short*)&e0; u.y = *(const unsigned short*)&e1;   \
            u.z = *(const unsigned short*)&e2; u.w = *(const unsigned short*)&e3;   \
            *(ushort4*)(yrow + DB * 32 + 8 * r4 + 4 * hi) = u;                      \
        }
    WRITE_DB(o0, 0) WRITE_DB(o1, 1) WRITE_DB(o2, 2) WRITE_DB(o3, 3)
    #undef WRITE_DB
}

extern "C" void kernel_launch(void* const* d_in, const int* in_sizes, int n_in,
                              void* d_out, int out_size, void* d_ws, size_t ws_size,
                              hipStream_t stream) {
    (void)in_sizes; (void)n_in; (void)out_size; (void)ws_size;
    const float* x  = (const float*)d_in[0];
    const float* wq = (const float*)d_in[1];
    const float* wk = (const float*)d_in[2];
    const float* wv = (const float*)d_in[3];
    const float* wp = (const float*)d_in[4];
    const float* qg = (const float*)d_in[5];
    float* out = (float*)d_out;

    char* ws = (char*)d_ws;
    size_t off = 0;
    auto alloc = [&](size_t bytes) { char* p = ws + off; off += (bytes + 255) & ~(size_t)255; return p; };

    __hip_bfloat16* xb  = (__hip_bfloat16*)alloc((size_t)BT_ * D_ * 2);
    __hip_bfloat16* wqb = (__hip_bfloat16*)alloc((size_t)D_ * D_ * 2);
    __hip_bfloat16* wkb = (__hip_bfloat16*)alloc((size_t)KD_ * D_ * 2);
    __hip_bfloat16* wvb = (__hip_bfloat16*)alloc((size_t)KD_ * D_ * 2);
    __hip_bfloat16* wpb = (__hip_bfloat16*)alloc((size_t)D_ * D_ * 2);
    float* qf = (float*)alloc((size_t)BT_ * D_ * 4);
    float* kf = (float*)alloc((size_t)BT_ * KD_ * 4);
    float* vf = (float*)alloc((size_t)BT_ * KD_ * 4);
    __hip_bfloat16* qbb = (__hip_bfloat16*)alloc((size_t)BT_ * D_ * 2);
    __hip_bfloat16* kbb = (__hip_bfloat16*)alloc((size_t)BT_ * KD_ * 2);
    // aliases (lifetimes disjoint on the sequential stream):
    __hip_bfloat16* ybb = xb;                   // yb written after xb's last read
    __hip_bfloat16* vbb = wqb;                  // wqb dead after q-projection
    __hip_bfloat16* vtb = wqb + (size_t)B_ * NKV_ * T_ * HD_;

    f2b_kernel<<<2048, 256, 0, stream>>>((const float4*)x,  (ushort4*)xb,  BT_ * D_ / 4);
    f2b_kernel<<<2048, 256, 0, stream>>>((const float4*)wq, (ushort4*)wqb, D_ * D_ / 4);
    f2b_kernel<<<2048, 256, 0, stream>>>((const float4*)wk, (ushort4*)wkb, KD_ * D_ / 4);
    f2b_kernel<<<2048, 256, 0, stream>>>((const float4*)wv, (ushort4*)wvb, KD_ * D_ / 4);
    f2b_kernel<<<2048, 256, 0, stream>>>((const float4*)wp, (ushort4*)wpb, D_ * D_ / 4);

    dim3 gq(BT_ / 128, D_ / 128);
    gemm_bt<<<gq, 256, 0, stream>>>(xb, wqb, qf, BT_, D_, D_);
    dim3 gkv(BT_ / 128, KD_ / 128);
    gemm_bt<<<gkv, 256, 0, stream>>>(xb, wkb, kf, BT_, KD_, D_);
    gemm_bt<<<gkv, 256, 0, stream>>>(xb, wvb, vf, BT_, KD_, D_);

    norm_rope<<<(BT_ * 24) / 4, 256, 0, stream>>>(qf, kf, vf, qg, qbb, kbb, vbb);

    dim3 gt(T_ / 32, HD_ / 32, B_ * NKV_);
    vtrans<<<gt, dim3(32, 8), 0, stream>>>(vbb, vtb);

    attn_fwd<<<512, 256, 0, stream>>>(qbb, kbb, vtb, ybb);

    gemm_bt<<<gq, 256, 0, stream>>>(ybb, wpb, out, BT_, D_, D_);
}

// Round 3
// 391.348 us; speedup vs baseline: 1.7988x; 1.0438x over previous
//
#include <hip/hip_runtime.h>
#include <hip/hip_bf16.h>

#define B_   2
#define T_   2048
#define D_   2048
#define NH_  16
#define NKV_ 4
#define HD_  128
#define KD_  512   // NKV*HD
#define BT_  4096  // B_*T_

typedef __bf16 bf16x8 __attribute__((ext_vector_type(8)));
typedef float  f32x4  __attribute__((ext_vector_type(4)));
typedef float  f32x16 __attribute__((ext_vector_type(16)));

__device__ __forceinline__ void gload_lds16(const __hip_bfloat16* g, __hip_bfloat16* l) {
    __builtin_amdgcn_global_load_lds(
        (__attribute__((address_space(1))) void*)(g),
        (__attribute__((address_space(3))) void*)(l),
        16, 0, 0);
}

// ---------------- fp32 -> bf16 convert ----------------
__global__ void f2b_kernel(const float4* __restrict__ in, ushort4* __restrict__ out, int n4) {
    int idx = blockIdx.x * blockDim.x + threadIdx.x;
    int stride = gridDim.x * blockDim.x;
    for (int j = idx; j < n4; j += stride) {
        float4 v = in[j];
        __hip_bfloat16 a = __float2bfloat16(v.x), b = __float2bfloat16(v.y),
                       c = __float2bfloat16(v.z), d = __float2bfloat16(v.w);
        ushort4 o;
        o.x = *(const unsigned short*)&a; o.y = *(const unsigned short*)&b;
        o.z = *(const unsigned short*)&c; o.w = *(const unsigned short*)&d;
        out[j] = o;
    }
}

// ---------------- GEMM: C(MxN) = A(MxK) * B(NxK)^T, bf16 in, f32 out ----------------
__global__ __launch_bounds__(256)
void gemm_bt(const __hip_bfloat16* __restrict__ A, const __hip_bfloat16* __restrict__ B,
             float* __restrict__ C, int M, int N, int K) {
    __shared__ __attribute__((aligned(16))) __hip_bfloat16 As[128 * 32];
    __shared__ __attribute__((aligned(16))) __hip_bfloat16 Bs[128 * 32];
    const int tid  = threadIdx.x;
    const int w    = tid >> 6;
    const int lane = tid & 63;
    const int lr   = lane & 15;
    const int lk   = lane >> 4;
    const int wr   = w >> 1, wc = w & 1;
    const size_t row0 = (size_t)blockIdx.x * 128;
    const size_t col0 = (size_t)blockIdx.y * 128;

    const __hip_bfloat16* ga = A + (row0 + tid / 4) * K + (tid % 4) * 8;
    const __hip_bfloat16* gb = B + (col0 + tid / 4) * K + (tid % 4) * 8;
    __hip_bfloat16* lA0 = &As[w * 512];
    __hip_bfloat16* lA1 = &As[2048 + w * 512];
    __hip_bfloat16* lB0 = &Bs[w * 512];
    __hip_bfloat16* lB1 = &Bs[2048 + w * 512];

    f32x4 acc[4][4] = {};
    for (int k0 = 0; k0 < K; k0 += 32) {
        gload_lds16(ga + k0,                 lA0);
        gload_lds16(ga + k0 + (size_t)64*K,  lA1);
        gload_lds16(gb + k0,                 lB0);
        gload_lds16(gb + k0 + (size_t)64*K,  lB1);
        __syncthreads();
        bf16x8 af[4], bfr[4];
        #pragma unroll
        for (int m = 0; m < 4; m++)
            af[m] = *(const bf16x8*)&As[(wr * 64 + m * 16 + lr) * 32 + lk * 8];
        #pragma unroll
        for (int n = 0; n < 4; n++)
            bfr[n] = *(const bf16x8*)&Bs[(wc * 64 + n * 16 + lr) * 32 + lk * 8];
        #pragma unroll
        for (int m = 0; m < 4; m++)
            #pragma unroll
            for (int n = 0; n < 4; n++)
                acc[m][n] = __builtin_amdgcn_mfma_f32_16x16x32_bf16(af[m], bfr[n], acc[m][n], 0, 0, 0);
        __syncthreads();
    }
    #pragma unroll
    for (int m = 0; m < 4; m++)
        #pragma unroll
        for (int n = 0; n < 4; n++)
            #pragma unroll
            for (int r = 0; r < 4; r++)
                C[(row0 + wr * 64 + m * 16 + lk * 4 + r) * N + col0 + wc * 64 + n * 16 + lr] = acc[m][n][r];
}

// ---------------- RMSNorm + partial RoPE + gain; v passthrough to bf16 ----------------
__global__ __launch_bounds__(256)
void norm_rope(const float* __restrict__ qf, const float* __restrict__ kf, const float* __restrict__ vf,
               const float* __restrict__ qg,
               __hip_bfloat16* __restrict__ qb, __hip_bfloat16* __restrict__ kb, __hip_bfloat16* __restrict__ vb) {
    int wid  = (blockIdx.x * 256 + threadIdx.x) >> 6;
    int lane = threadIdx.x & 63;
    int bt = wid / 24, hh = wid % 24;
    int b = bt >> 11, t = bt & (T_ - 1);

    const float* row;
    if (hh < NH_)            row = qf + (size_t)bt * D_  + hh * HD_;
    else if (hh < NH_+NKV_)  row = kf + (size_t)bt * KD_ + (hh - NH_) * HD_;
    else                     row = vf + (size_t)bt * KD_ + (hh - NH_ - NKV_) * HD_;

    float2 xv = *(const float2*)(row + lane * 2);

    if (hh >= NH_ + NKV_) {  // v: just convert
        int kv = hh - NH_ - NKV_;
        __hip_bfloat16* o = vb + ((size_t)(b * NKV_ + kv) * T_ + t) * HD_ + lane * 2;
        o[0] = __float2bfloat16(xv.x); o[1] = __float2bfloat16(xv.y);
        return;
    }

    float ss = xv.x * xv.x + xv.y * xv.y;
    #pragma unroll
    for (int off = 32; off; off >>= 1) ss += __shfl_xor(ss, off);
    float rn = rsqrtf(ss * (1.0f / HD_) + 1.1920929e-7f);
    float y0 = xv.x * rn, y1 = xv.y * rn;

    float py0 = __shfl_xor(y0, 4), py1 = __shfl_xor(y1, 4);
    float o0 = y0, o1 = y1;
    if (lane < 8) {
        int i0 = (2 * lane) & 7;
        float f0 = (float)t * exp2f(-(float)i0       * 1.66096404744368f);
        float f1 = (float)t * exp2f(-(float)(i0 + 1) * 1.66096404744368f);
        float s0, c0, s1, c1;
        sincosf(f0, &s0, &c0);
        sincosf(f1, &s1, &c1);
        if (lane < 4) { o0 =  y0 * c0 + py0 * s0; o1 =  y1 * c1 + py1 * s1; }
        else          { o0 = -y0 * c0 + py0 * s0; o1 = -y1 * c1 + py1 * s1; }
    }

    if (hh < NH_) {
        // fold gain * 1/sqrt(HD) * log2(e) into q
        float g = qg[hh] * 0.1275174305f;
        o0 *= g; o1 *= g;
        __hip_bfloat16* o = qb + ((size_t)(b * NH_ + hh) * T_ + t) * HD_ + lane * 2;
        o[0] = __float2bfloat16(o0); o[1] = __float2bfloat16(o1);
    } else {
        int kv = hh - NH_;
        __hip_bfloat16* o = kb + ((size_t)(b * NKV_ + kv) * T_ + t) * HD_ + lane * 2;
        o[0] = __float2bfloat16(o0); o[1] = __float2bfloat16(o1);
    }
}

// ---------------- V transpose: [bk][T][HD] -> [bk][HD][T] ----------------
__global__ void vtrans(const __hip_bfloat16* __restrict__ vb, __hip_bfloat16* __restrict__ vt) {
    __shared__ __hip_bfloat16 tile[32][33];
    int bk = blockIdx.z;
    int t0 = blockIdx.x * 32, h0 = blockIdx.y * 32;
    int tx = threadIdx.x, ty = threadIdx.y;  // 32 x 8
    const __hip_bfloat16* src = vb + ((size_t)bk * T_ + t0) * HD_ + h0;
    #pragma unroll
    for (int j = 0; j < 4; j++) tile[ty + j * 8][tx] = src[(size_t)(ty + j * 8) * HD_ + tx];
    __syncthreads();
    __hip_bfloat16* dst = vt + ((size_t)bk * HD_ + h0) * T_ + t0;
    #pragma unroll
    for (int j = 0; j < 4; j++) dst[(size_t)(ty + j * 8) * T_ + tx] = tile[tx][ty + j * 8];
}

// ---------------- causal GQA flash attention (swapped-QK, 32x32 MFMA, no LDS) ----------------
__device__ __forceinline__ unsigned pkbf(float a, float b) {
    __hip_bfloat16 x = __float2bfloat16(a), y = __float2bfloat16(b);
    unsigned short xu = *(const unsigned short*)&x, yu = *(const unsigned short*)&y;
    return (unsigned)xu | ((unsigned)yu << 16);
}

union U8u { unsigned u[4]; bf16x8 v; };

// One WAVE per block (64 threads). 2048 blocks, LPT order (longest q-chunk first),
// XCD-grouped so each (b,kv-head)'s K/V stays in one XCD's L2.
__global__ __launch_bounds__(64, 2)
void attn_fwd(const __hip_bfloat16* __restrict__ qb, const __hip_bfloat16* __restrict__ kb,
              const __hip_bfloat16* __restrict__ vt, __hip_bfloat16* __restrict__ yb) {
    const int lane = threadIdx.x & 63;
    const int l31 = lane & 31, hi = lane >> 5;
    const int bid = blockIdx.x;
    const int xcd = bid & 7;               // = b*4 + kvh  (round-robin XCD assignment)
    const int b = xcd >> 2, kvh = xcd & 3;
    const int idx = bid >> 3;              // 0..255
    const int g = idx & 3;                 // head within kv group
    const int h = kvh * 4 + g;
    const int c = 63 - (idx >> 2);         // LPT: first blocks get longest chunks
    const int qa = c * 32;

    const __hip_bfloat16* qp = qb + ((size_t)(b * NH_ + h) * T_ + qa) * HD_;
    const __hip_bfloat16* kp = kb + (size_t)(b * NKV_ + kvh) * T_ * HD_;
    const __hip_bfloat16* vp = vt + (size_t)(b * NKV_ + kvh) * HD_ * T_ + (size_t)l31 * T_;

    bf16x8 qfr[8];
    #pragma unroll
    for (int hb = 0; hb < 8; ++hb)
        qfr[hb] = *(const bf16x8*)(qp + (size_t)l31 * HD_ + hb * 16 + hi * 8);

    f32x16 o0 = {}, o1 = {}, o2 = {}, o3 = {};
    float m = -1e30f, s = 0.f;

    // K-fragment double buffer (static arrays, loop unrolled x2 -> no reg copies)
    bf16x8 ka[8], kb2[8];
    {
        const __hip_bfloat16* kpt = kp + (size_t)l31 * HD_ + hi * 8;
        #pragma unroll
        for (int hb = 0; hb < 8; ++hb) ka[hb] = *(const bf16x8*)(kpt + hb * 16);
    }

    auto process = [&](int kt, const bf16x8 (&kfr)[8]) {
        const int kvb = kt * 32;
        // S^T[kv][q] = sum_hd K[kv][hd] * Q[q][hd]
        f32x16 sa = {};
        __builtin_amdgcn_s_setprio(1);
        #pragma unroll
        for (int hb = 0; hb < 8; ++hb)
            sa = __builtin_amdgcn_mfma_f32_32x32x16_bf16(kfr[hb], qfr[hb], sa, 0, 0, 0);
        __builtin_amdgcn_s_setprio(0);
        if (kt == c) {  // diagonal tile: mask kv > q (relative indices)
            #pragma unroll
            for (int r = 0; r < 16; ++r) {
                int kvrel = (r & 3) + 8 * (r >> 2) + 4 * hi;
                if (kvrel > l31) sa[r] = -1e30f;
            }
        }
        float pm = sa[0];
        #pragma unroll
        for (int r = 1; r < 16; ++r) pm = fmaxf(pm, sa[r]);
        pm = fmaxf(pm, __shfl_xor(pm, 32));
        if (!__all(pm <= m + 8.f)) {   // deferred rescale (THR=8 in log2 domain)
            float mn = fmaxf(m, pm);
            float corr = exp2f(m - mn);
            s *= corr;
            #pragma unroll
            for (int r = 0; r < 16; ++r) { o0[r] *= corr; o1[r] *= corr; o2[r] *= corr; o3[r] *= corr; }
            m = mn;
        }
        float p[16]; float rs = 0.f;
        #pragma unroll
        for (int r = 0; r < 16; ++r) { p[r] = exp2f(sa[r] - m); rs += p[r]; }
        rs += __shfl_xor(rs, 32);
        s += rs;
        // pack P -> bf16 PV B-fragments (lane pair l <-> l^32 exchange)
        unsigned pk[8];
        #pragma unroll
        for (int jj = 0; jj < 8; ++jj) pk[jj] = pkbf(p[2 * jj], p[2 * jj + 1]);
        unsigned pks[8];
        #pragma unroll
        for (int jj = 0; jj < 8; ++jj) pks[jj] = (unsigned)__shfl_xor((int)pk[jj], 32);
        U8u pa0, pa1;
        pa0.u[0] = hi ? pks[2] : pk[0];
        pa0.u[1] = hi ? pks[3] : pk[1];
        pa0.u[2] = hi ? pk[2]  : pks[0];
        pa0.u[3] = hi ? pk[3]  : pks[1];
        pa1.u[0] = hi ? pks[6] : pk[4];
        pa1.u[1] = hi ? pks[7] : pk[5];
        pa1.u[2] = hi ? pk[6]  : pks[4];
        pa1.u[3] = hi ? pk[7]  : pks[5];
        // O^T[d][q] += V^T[d][kv] * P[kv][q]
        const __hip_bfloat16* vpt = vp + kvb + hi * 8;
        __builtin_amdgcn_s_setprio(1);
        {
            bf16x8 vf0 = *(const bf16x8*)(vpt);
            bf16x8 vf1 = *(const bf16x8*)(vpt + 16);
            o0 = __builtin_amdgcn_mfma_f32_32x32x16_bf16(vf0, pa0.v, o0, 0, 0, 0);
            o0 = __builtin_amdgcn_mfma_f32_32x32x16_bf16(vf1, pa1.v, o0, 0, 0, 0);
        }
        {
            bf16x8 vf0 = *(const bf16x8*)(vpt + (size_t)32 * T_);
            bf16x8 vf1 = *(const bf16x8*)(vpt + (size_t)32 * T_ + 16);
            o1 = __builtin_amdgcn_mfma_f32_32x32x16_bf16(vf0, pa0.v, o1, 0, 0, 0);
            o1 = __builtin_amdgcn_mfma_f32_32x32x16_bf16(vf1, pa1.v, o1, 0, 0, 0);
        }
        {
            bf16x8 vf0 = *(const bf16x8*)(vpt + (size_t)64 * T_);
            bf16x8 vf1 = *(const bf16x8*)(vpt + (size_t)64 * T_ + 16);
            o2 = __builtin_amdgcn_mfma_f32_32x32x16_bf16(vf0, pa0.v, o2, 0, 0, 0);
            o2 = __builtin_amdgcn_mfma_f32_32x32x16_bf16(vf1, pa1.v, o2, 0, 0, 0);
        }
        {
            bf16x8 vf0 = *(const bf16x8*)(vpt + (size_t)96 * T_);
            bf16x8 vf1 = *(const bf16x8*)(vpt + (size_t)96 * T_ + 16);
            o3 = __builtin_amdgcn_mfma_f32_32x32x16_bf16(vf0, pa0.v, o3, 0, 0, 0);
            o3 = __builtin_amdgcn_mfma_f32_32x32x16_bf16(vf1, pa1.v, o3, 0, 0, 0);
        }
        __builtin_amdgcn_s_setprio(0);
    };

    auto loadK = [&](int kt, bf16x8 (&dst)[8]) {
        const __hip_bfloat16* kpt = kp + (size_t)(kt * 32 + l31) * HD_ + hi * 8;
        #pragma unroll
        for (int hb = 0; hb < 8; ++hb) dst[hb] = *(const bf16x8*)(kpt + hb * 16);
    };

    int kt = 0;
    while (true) {
        // buffer A holds tile kt; prefetch kt+1 into B, then process kt
        loadK(kt < c ? kt + 1 : kt, kb2);
        process(kt, ka);
        ++kt;
        if (kt > c) break;
        loadK(kt < c ? kt + 1 : kt, ka);
        process(kt, kb2);
        ++kt;
        if (kt > c) break;
    }

    float inv = 1.0f / s;
    __hip_bfloat16* yrow = yb + ((size_t)b * T_ + qa + l31) * D_ + h * HD_;
    #define WRITE_DB(ON, DB)                                                        \
        _Pragma("unroll")                                                           \
        for (int r4 = 0; r4 < 4; ++r4) {                                            \
            ushort4 u;                                                              \
            __hip_bfloat16 e0 = __float2bfloat16(ON[4*r4+0] * inv);                 \
            __hip_bfloat16 e1 = __float2bfloat16(ON[4*r4+1] * inv);                 \
            __hip_bfloat16 e2 = __float2bfloat16(ON[4*r4+2] * inv);                 \
            __hip_bfloat16 e3 = __float2bfloat16(ON[4*r4+3] * inv);                 \
            u.x = *(const unsigned short*)&e0; u.y = *(const unsigned short*)&e1;   \
            u.z = *(const unsigned short*)&e2; u.w = *(const unsigned short*)&e3;   \
            *(ushort4*)(yrow + DB * 32 + 8 * r4 + 4 * hi) = u;                      \
        }
    WRITE_DB(o0, 0) WRITE_DB(o1, 1) WRITE_DB(o2, 2) WRITE_DB(o3, 3)
    #undef WRITE_DB
}

extern "C" void kernel_launch(void* const* d_in, const int* in_sizes, int n_in,
                              void* d_out, int out_size, void* d_ws, size_t ws_size,
                              hipStream_t stream) {
    (void)in_sizes; (void)n_in; (void)out_size; (void)ws_size;
    const float* x  = (const float*)d_in[0];
    const float* wq = (const float*)d_in[1];
    const float* wk = (const float*)d_in[2];
    const float* wv = (const float*)d_in[3];
    const float* wp = (const float*)d_in[4];
    const float* qg = (const float*)d_in[5];
    float* out = (float*)d_out;

    char* ws = (char*)d_ws;
    size_t off = 0;
    auto alloc = [&](size_t bytes) { char* p = ws + off; off += (bytes + 255) & ~(size_t)255; return p; };

    __hip_bfloat16* xb  = (__hip_bfloat16*)alloc((size_t)BT_ * D_ * 2);
    __hip_bfloat16* wqb = (__hip_bfloat16*)alloc((size_t)D_ * D_ * 2);
    __hip_bfloat16* wkb = (__hip_bfloat16*)alloc((size_t)KD_ * D_ * 2);
    __hip_bfloat16* wvb = (__hip_bfloat16*)alloc((size_t)KD_ * D_ * 2);
    __hip_bfloat16* wpb = (__hip_bfloat16*)alloc((size_t)D_ * D_ * 2);
    float* qf = (float*)alloc((size_t)BT_ * D_ * 4);
    float* kf = (float*)alloc((size_t)BT_ * KD_ * 4);
    float* vf = (float*)alloc((size_t)BT_ * KD_ * 4);
    __hip_bfloat16* qbb = (__hip_bfloat16*)alloc((size_t)BT_ * D_ * 2);
    __hip_bfloat16* kbb = (__hip_bfloat16*)alloc((size_t)BT_ * KD_ * 2);
    // aliases (lifetimes disjoint on the sequential stream):
    __hip_bfloat16* ybb = xb;                   // yb written after xb's last read
    __hip_bfloat16* vbb = wqb;                  // wqb dead after q-projection
    __hip_bfloat16* vtb = wqb + (size_t)B_ * NKV_ * T_ * HD_;

    f2b_kernel<<<2048, 256, 0, stream>>>((const float4*)x,  (ushort4*)xb,  BT_ * D_ / 4);
    f2b_kernel<<<2048, 256, 0, stream>>>((const float4*)wq, (ushort4*)wqb, D_ * D_ / 4);
    f2b_kernel<<<2048, 256, 0, stream>>>((const float4*)wk, (ushort4*)wkb, KD_ * D_ / 4);
    f2b_kernel<<<2048, 256, 0, stream>>>((const float4*)wv, (ushort4*)wvb, KD_ * D_ / 4);
    f2b_kernel<<<2048, 256, 0, stream>>>((const float4*)wp, (ushort4*)wpb, D_ * D_ / 4);

    dim3 gq(BT_ / 128, D_ / 128);
    gemm_bt<<<gq, 256, 0, stream>>>(xb, wqb, qf, BT_, D_, D_);
    dim3 gkv(BT_ / 128, KD_ / 128);
    gemm_bt<<<gkv, 256, 0, stream>>>(xb, wkb, kf, BT_, KD_, D_);
    gemm_bt<<<gkv, 256, 0, stream>>>(xb, wvb, vf, BT_, KD_, D_);

    norm_rope<<<(BT_ * 24) / 4, 256, 0, stream>>>(qf, kf, vf, qg, qbb, kbb, vbb);

    dim3 gt(T_ / 32, HD_ / 32, B_ * NKV_);
    vtrans<<<gt, dim3(32, 8), 0, stream>>>(vbb, vtb);

    attn_fwd<<<2048, 64, 0, stream>>>(qbb, kbb, vtb, ybb);

    gemm_bt<<<gq, 256, 0, stream>>>(ybb, wpb, out, BT_, D_, D_);
}